// Round 1
// baseline (11.548 us; speedup 1.0000x reference)
//
#include <hip/hip_runtime.h>

#define BATCH 512
#define DIMS  2048

// Kernel 1: one block per sample. dist[b] = clip(||f_b - c_{t_b}||^2)
__global__ __launch_bounds__(256) void center_dist_kernel(
        const float* __restrict__ features,
        const float* __restrict__ centers,
        const int* __restrict__ targets,
        float* __restrict__ dists) {
    const int b = blockIdx.x;
    const int t = targets[b];
    const float4* f = reinterpret_cast<const float4*>(features + (size_t)b * DIMS);
    const float4* c = reinterpret_cast<const float4*>(centers + (size_t)t * DIMS);

    float acc = 0.f;
    // DIMS/4 = 512 float4 elements; 256 threads -> 2 iterations each.
    #pragma unroll 2
    for (int i = threadIdx.x; i < DIMS / 4; i += 256) {
        float4 fv = f[i];
        float4 cv = c[i];
        float dx = fv.x - cv.x;
        float dy = fv.y - cv.y;
        float dz = fv.z - cv.z;
        float dw = fv.w - cv.w;
        acc += dx * dx + dy * dy + dz * dz + dw * dw;
    }

    // wave-64 butterfly reduce
    #pragma unroll
    for (int off = 32; off > 0; off >>= 1) acc += __shfl_down(acc, off, 64);

    __shared__ float s[4];
    const int lane = threadIdx.x & 63;
    const int wid  = threadIdx.x >> 6;
    if (lane == 0) s[wid] = acc;
    __syncthreads();
    if (threadIdx.x == 0) {
        float d = s[0] + s[1] + s[2] + s[3];
        d = fminf(fmaxf(d, 1e-12f), 1e12f);
        dists[b] = d;
    }
}

// Kernel 2: single block, mean over BATCH dists.
__global__ __launch_bounds__(256) void mean_kernel(
        const float* __restrict__ dists,
        float* __restrict__ out) {
    float acc = 0.f;
    #pragma unroll 2
    for (int i = threadIdx.x; i < BATCH; i += 256) acc += dists[i];

    #pragma unroll
    for (int off = 32; off > 0; off >>= 1) acc += __shfl_down(acc, off, 64);

    __shared__ float s[4];
    const int lane = threadIdx.x & 63;
    const int wid  = threadIdx.x >> 6;
    if (lane == 0) s[wid] = acc;
    __syncthreads();
    if (threadIdx.x == 0) out[0] = (s[0] + s[1] + s[2] + s[3]) * (1.0f / BATCH);
}

extern "C" void kernel_launch(void* const* d_in, const int* in_sizes, int n_in,
                              void* d_out, int out_size, void* d_ws, size_t ws_size,
                              hipStream_t stream) {
    const float* features = (const float*)d_in[0];
    const float* centers  = (const float*)d_in[1];
    const int*   targets  = (const int*)d_in[2];
    float* out   = (float*)d_out;
    float* dists = (float*)d_ws;   // 512 floats = 2 KB scratch

    center_dist_kernel<<<BATCH, 256, 0, stream>>>(features, centers, targets, dists);
    mean_kernel<<<1, 256, 0, stream>>>(dists, out);
}